// Round 3
// baseline (603.639 us; speedup 1.0000x reference)
//
#include <hip/hip_runtime.h>
#include <stdint.h>

// Triaffine: out[b,z,x,y] = sum_{i,j,k} xb[x,i] z[z,k] W[i,k,j] yb[y,j]
// B=4, S=128, D=512.  W: [513][512][513] f32 (i,k,j), elem (i,k,j) at (i*512+k)*513+j.
//
// Decomposition (bias split so all GEMM dims are 512):
//   M[bz,i,j] = sum_k z[bz,k] W[i,k,j]        (i,j < 512)   -- kernel G1, bf16 out
//   per bz:  R[i,y] = sum_j M[i,j] Ybf[y,j]                  -- kernel G2 pass-2
//            out[x,y] = sum_i Xbf[x,i] R[i,y] + u[x]+v[y]+d  -- kernel G2 pass-3
//   a[bz,i] = sum_k z W[i,k,512], c[bz,j] = sum_k z W[512,k,j], d = sum_k z W[512,k,512]

typedef __attribute__((ext_vector_type(8))) short bf16x8;
typedef __attribute__((ext_vector_type(4))) float f32x4;

__device__ __forceinline__ unsigned short f2bf(float f) {
    unsigned int u = __float_as_uint(f);
    u += 0x7fffu + ((u >> 16) & 1u);      // RNE
    return (unsigned short)(u >> 16);
}

__device__ __forceinline__ void gload_lds16(const void* g, void* l) {
    __builtin_amdgcn_global_load_lds((const __attribute__((address_space(1))) void*)g,
                                     (__attribute__((address_space(3))) void*)l, 16, 0, 0);
}

// ---------------- cast x,y,z -> bf16 ----------------
__global__ __launch_bounds__(256) void k_cast(const float* __restrict__ x,
    const float* __restrict__ y, const float* __restrict__ z,
    unsigned short* __restrict__ xbf, unsigned short* __restrict__ ybf,
    unsigned short* __restrict__ zbf)
{
    int t = blockIdx.x * 256 + threadIdx.x;   // 98304 threads, 8 elems each
    int arr = t >> 15;
    int off = (t & 32767) * 8;
    const float* src = (arr == 0) ? x : (arr == 1) ? y : z;
    unsigned short* dst = (arr == 0) ? xbf : (arr == 1) ? ybf : zbf;
    float4 a = *(const float4*)(src + off);
    float4 b = *(const float4*)(src + off + 4);
    uint4 o;
    o.x = f2bf(a.x) | ((unsigned)f2bf(a.y) << 16);
    o.y = f2bf(a.z) | ((unsigned)f2bf(a.w) << 16);
    o.z = f2bf(b.x) | ((unsigned)f2bf(b.y) << 16);
    o.w = f2bf(b.z) | ((unsigned)f2bf(b.w) << 16);
    *(uint4*)(dst + off) = o;
}

// ---------------- bias-edge GEMMs ----------------
__global__ __launch_bounds__(256) void k_edge(const float* __restrict__ z,
    const float* __restrict__ w, float* __restrict__ a_arr,
    float* __restrict__ c_arr, float* __restrict__ d_arr)
{
    __shared__ float Zs[64][33];
    __shared__ float Bs[32][65];
    int t = threadIdx.x;
    int mb = blockIdx.x % 17, bzb = blockIdx.x / 17;
    int tr = t >> 4, tc = t & 15;
    float acc[4][4] = {};
    for (int k0 = 0; k0 < 512; k0 += 32) {
        __syncthreads();
        {   int row = t >> 2, ko = (t & 3) * 8;
            const float* p = z + (bzb * 64 + row) * 512 + k0 + ko;
            float4 v0 = ((const float4*)p)[0], v1 = ((const float4*)p)[1];
            Zs[row][ko + 0] = v0.x; Zs[row][ko + 1] = v0.y; Zs[row][ko + 2] = v0.z; Zs[row][ko + 3] = v0.w;
            Zs[row][ko + 4] = v1.x; Zs[row][ko + 5] = v1.y; Zs[row][ko + 6] = v1.z; Zs[row][ko + 7] = v1.w;
        }
        {   int kr = t >> 3, mo = (t & 7) * 8;
            for (int e = 0; e < 8; ++e) {
                int m = mb * 64 + mo + e;
                float v = 0.f;
                int krow = k0 + kr;
                if (m < 512)        v = w[(m * 512 + krow) * 513 + 512];
                else if (m < 1024)  v = w[(262144 + krow) * 513 + (m - 512)];
                else if (m == 1024) v = w[(262144 + krow) * 513 + 512];
                Bs[kr][mo + e] = v;
            }
        }
        __syncthreads();
        for (int kk = 0; kk < 32; ++kk) {
            float zr[4], br[4];
            for (int r = 0; r < 4; ++r) zr[r] = Zs[tr * 4 + r][kk];
            for (int c = 0; c < 4; ++c) br[c] = Bs[kk][tc * 4 + c];
            for (int r = 0; r < 4; ++r)
                for (int c = 0; c < 4; ++c) acc[r][c] += zr[r] * br[c];
        }
    }
    for (int r = 0; r < 4; ++r)
        for (int c = 0; c < 4; ++c) {
            int bz = bzb * 64 + tr * 4 + r;
            int m = mb * 64 + tc * 4 + c;
            if (m < 512)        a_arr[bz * 512 + m] = acc[r][c];
            else if (m < 1024)  c_arr[bz * 512 + (m - 512)] = acc[r][c];
            else if (m == 1024) d_arr[bz] = acc[r][c];
        }
}

// ---------------- G1: M[bz, i_local, j] = Z(bf16) x W(f32->bf16) ----------------
// BM=512 (all bz; W streamed exactly once), BN=64, BK=32, 16 K-steps.
// 8 waves = 4 bz-grp x 2 j-grp; wave tile 128bz x 32j; acc[8][2].
// T3/T4 pipeline, fully unrolled:
//   step ks: issue Z glds(ks+1)->Zb[cur^1]; issue W loads(ks+2)->wr[cur];
//            ds_read frags + 16 MFMA on Zb[cur]/Bb[cur];
//            pack W(ks+1)->Bb[cur^1] (compiler's counted vmcnt leaves prefetch alive);
//            s_waitcnt vmcnt(4) lgkmcnt(0); raw s_barrier.   [invariant: W(ks+1) in flight]
// LDS XOR swizzle (2-way-free): slot = l4 ^ ((row>>1)&3), rows 64 B.
__global__ __launch_bounds__(512, 4) void k_gemm1(const unsigned short* __restrict__ zbf,
    const float* __restrict__ w, unsigned short* __restrict__ Mws,
    int i0, int chi)
{
    extern __shared__ unsigned char smem[];
    unsigned char* Zb0 = smem;                 // [512 rows][32 k] bf16 = 32 KB
    unsigned char* Zb1 = smem + 32768;
    unsigned char* Bb0 = smem + 65536;         // [64 j][32 k] bf16 = 4 KB
    unsigned char* Bb1 = smem + 69632;         // total 73728 B

    int nwg = gridDim.x;
    int cpx = nwg >> 3;
    int bid = blockIdx.x;
    int swz = (bid & 7) * cpx + (bid >> 3);    // XCD swizzle (nwg % 8 == 0)
    int iloc = swz >> 3, jb = swz & 7;
    int j0 = jb * 64;
    int t = threadIdx.x, wid = t >> 6, lane = t & 63;
    int bzg = wid >> 1, jg = wid & 1;
    int l15 = lane & 15, l4 = lane >> 4;

    // Z staging source mapping (pre-swizzled; linear LDS dest => swizzled layout)
    int arow = lane >> 2;                      // row within 16-row block
    int akc  = (lane & 3) ^ ((lane >> 3) & 3); // 16B k-chunk, slot = chunk ^ ((row>>1)&3)
    const unsigned short* zbase = zbf + (size_t)(wid * 64 + arow) * 512 + akc * 8;

    // W staging: thread t -> j = t&63, k-quad kq = t>>6 (4 scalar loads, 1 b64 LDS write)
    int jB = t & 63, kq = t >> 6;
    const float* wb = w + (size_t)(i0 + iloc) * 262656 + (size_t)(kq * 4) * 513 + j0 + jB;
    int bwoff = jB * 64 + (((kq >> 1) ^ ((jB >> 1) & 3)) * 16) + (kq & 1) * 8;

    // fragment read offsets (swizzled); mt/nt stride = 16 rows * 64 B = 1024
    int aoff = (bzg * 128 + l15) * 64 + ((l4 ^ ((l15 >> 1) & 3)) * 16);
    int boff = (jg * 32 + l15) * 64 + ((l4 ^ ((l15 >> 1) & 3)) * 16);

    f32x4 acc[8][2];
    #pragma unroll
    for (int mt = 0; mt < 8; ++mt)
        #pragma unroll
        for (int nt = 0; nt < 2; ++nt) acc[mt][nt] = (f32x4){0.f, 0.f, 0.f, 0.f};

    float wr[2][4];

    // ---- prologue: Z(0) glds, W(0) and W(1) reg loads, pack W(0) ----
    #pragma unroll
    for (int q = 0; q < 4; ++q)
        gload_lds16(zbase + q * 8192, Zb0 + wid * 4096 + q * 1024);
    {
        #pragma unroll
        for (int e = 0; e < 4; ++e) wr[0][e] = wb[(size_t)e * 513];
        const float* wp = wb + (size_t)32 * 513;
        #pragma unroll
        for (int e = 0; e < 4; ++e) wr[1][e] = wp[(size_t)e * 513];
        // pack W(0): compiler inserts counted vmcnt (drains Z(0)+W(0), leaves W(1))
        unsigned p0 = f2bf(wr[0][0]) | ((unsigned)f2bf(wr[0][1]) << 16);
        unsigned p1 = f2bf(wr[0][2]) | ((unsigned)f2bf(wr[0][3]) << 16);
        *(uint2*)(Bb0 + bwoff) = make_uint2(p0, p1);
    }
    asm volatile("s_waitcnt lgkmcnt(0)" ::: "memory");
    __builtin_amdgcn_s_barrier();
    __builtin_amdgcn_sched_barrier(0);

    #pragma unroll
    for (int ks = 0; ks < 16; ++ks) {
        const int cur = ks & 1;
        unsigned char* Zcur  = cur ? Zb1 : Zb0;
        unsigned char* Znext = cur ? Zb0 : Zb1;
        unsigned char* Bcur  = cur ? Bb1 : Bb0;
        unsigned char* Bnext = cur ? Bb0 : Bb1;

        // 1. issue Z(ks+1) -> Znext
        if (ks < 15) {
            #pragma unroll
            for (int q = 0; q < 4; ++q)
                gload_lds16(zbase + (ks + 1) * 32 + q * 8192, Znext + wid * 4096 + q * 1024);
        }
        // 2. issue W(ks+2) -> wr[cur] (2-deep prefetch)
        if (ks < 14) {
            const float* wp = wb + (size_t)(ks + 2) * 32 * 513;
            #pragma unroll
            for (int e = 0; e < 4; ++e) wr[cur][e] = wp[(size_t)e * 513];
        }
        // 3. compute on current buffers
        bf16x8 bfr0 = *(const bf16x8*)(Bcur + boff);
        bf16x8 bfr1 = *(const bf16x8*)(Bcur + boff + 1024);
        #pragma unroll
        for (int mt = 0; mt < 8; ++mt) {
            bf16x8 afr = *(const bf16x8*)(Zcur + aoff + mt * 1024);
            acc[mt][0] = __builtin_amdgcn_mfma_f32_16x16x32_bf16(afr, bfr0, acc[mt][0], 0, 0, 0);
            acc[mt][1] = __builtin_amdgcn_mfma_f32_16x16x32_bf16(afr, bfr1, acc[mt][1], 0, 0, 0);
        }
        // 4. pack W(ks+1) -> Bnext (compiler's counted wait drains only W(ks+1))
        if (ks < 15) {
            unsigned p0 = f2bf(wr[cur ^ 1][0]) | ((unsigned)f2bf(wr[cur ^ 1][1]) << 16);
            unsigned p1 = f2bf(wr[cur ^ 1][2]) | ((unsigned)f2bf(wr[cur ^ 1][3]) << 16);
            *(uint2*)(Bnext + bwoff) = make_uint2(p0, p1);
        }
        // 5. counted-vmcnt barrier: drain Z(ks+1) glds + ds_write, keep W(ks+2) in flight
        if (ks < 14) {
            asm volatile("s_waitcnt vmcnt(4) lgkmcnt(0)" ::: "memory");
        } else if (ks == 14) {
            asm volatile("s_waitcnt vmcnt(0) lgkmcnt(0)" ::: "memory");
        }
        if (ks < 15) {
            __builtin_amdgcn_s_barrier();
            __builtin_amdgcn_sched_barrier(0);
        }
    }

    // ---- epilogue: store M[bz][iloc][j] bf16 ----
    size_t mrow = (size_t)chi * 512;
    #pragma unroll
    for (int mt = 0; mt < 8; ++mt)
        #pragma unroll
        for (int nt = 0; nt < 2; ++nt)
            #pragma unroll
            for (int r = 0; r < 4; ++r) {
                int bz = bzg * 128 + mt * 16 + l4 * 4 + r;
                int j  = j0 + jg * 32 + nt * 16 + l15;
                Mws[(size_t)bz * mrow + (size_t)iloc * 512 + j] = f2bf(acc[mt][nt][r]);
            }
}

// ---------------- G2: per-bz fused  R = M x Y^T ;  out += X x R  (+bias terms) ----------------
__global__ __launch_bounds__(512) void k_fuse(const unsigned short* __restrict__ xbf,
    const unsigned short* __restrict__ ybf, const unsigned short* __restrict__ Mws,
    const float* __restrict__ xf, const float* __restrict__ yf,
    const float* __restrict__ a_arr, const float* __restrict__ c_arr,
    const float* __restrict__ d_arr, float* __restrict__ out,
    int i0, int nib, int chi, int first)
{
    __shared__ unsigned short Xlds[128 * 72];   // [x][i]  stride 72 ush = 144 B
    __shared__ unsigned short Ylds[128 * 72];   // [y][j]
    __shared__ unsigned short Mlds[64 * 72];    // [i][j]
    __shared__ unsigned short Rlds[128 * 72];   // [y][i]
    int bid = blockIdx.x;
    int bz = (bid & 7) * 64 + (bid >> 3);       // XCD swizzle
    int b = bz >> 7;
    int t = threadIdx.x;
    int wid = t >> 6, lane = t & 63;
    int l15 = lane & 15, l4 = lane >> 4;
    int xg = wid >> 2, yg = wid & 3;

    f32x4 acc[4][2];
    if (first) {
        float* part = (float*)Xlds;             // 512 f32
        float* uv = (float*)Ylds;               // u[128], v[128]
        int xr = t & 127, q = t >> 7;
        {   const float* xp = xf + (size_t)(b * 128 + xr) * 512 + q * 128;
            const float* ap = a_arr + bz * 512 + q * 128;
            float s = 0.f;
            for (int ii = 0; ii < 128; ++ii) s += xp[ii] * ap[ii];
            part[q * 128 + xr] = s;
        }
        __syncthreads();
        if (t < 128) uv[t] = part[t] + part[128 + t] + part[256 + t] + part[384 + t];
        __syncthreads();
        {   const float* yp = yf + (size_t)(b * 128 + xr) * 512 + q * 128;
            const float* cp = c_arr + bz * 512 + q * 128;
            float s = 0.f;
            for (int ii = 0; ii < 128; ++ii) s += yp[ii] * cp[ii];
            part[q * 128 + xr] = s;
        }
        __syncthreads();
        if (t < 128) uv[128 + t] = part[t] + part[128 + t] + part[256 + t] + part[384 + t];
        __syncthreads();
        float dv = d_arr[bz];
        for (int mt = 0; mt < 4; ++mt)
            for (int nt = 0; nt < 2; ++nt) {
                int y = yg * 32 + nt * 16 + l15;
                for (int r = 0; r < 4; ++r) {
                    int x = xg * 64 + mt * 16 + l4 * 4 + r;
                    acc[mt][nt][r] = uv[x] + uv[128 + y] + dv;
                }
            }
    } else {
        for (int mt = 0; mt < 4; ++mt) for (int nt = 0; nt < 2; ++nt) acc[mt][nt] = (f32x4){0.f,0.f,0.f,0.f};
    }

    for (int ibl = 0; ibl < nib; ++ibl) {
        __syncthreads();
        {   int xr = t >> 2, io = (t & 3) * 16;
            const uint4* src = (const uint4*)(xbf + (size_t)(b * 128 + xr) * 512 + i0 + ibl * 64 + io);
            uint4 v0 = src[0], v1 = src[1];
            uint4* dst = (uint4*)(Xlds + xr * 72 + io);
            dst[0] = v0; dst[1] = v1;
        }
        f32x4 accR[2][2];
        for (int mt = 0; mt < 2; ++mt) for (int nt = 0; nt < 2; ++nt) accR[mt][nt] = (f32x4){0.f,0.f,0.f,0.f};

        for (int jbk = 0; jbk < 8; ++jbk) {
            __syncthreads();
            {   int yr = t >> 2, jo = (t & 3) * 16;
                const uint4* src = (const uint4*)(ybf + (size_t)(b * 128 + yr) * 512 + jbk * 64 + jo);
                uint4 v0 = src[0], v1 = src[1];
                uint4* dst = (uint4*)(Ylds + yr * 72 + jo);
                dst[0] = v0; dst[1] = v1;
            }
            {   int ir = t >> 3, jo = (t & 7) * 8;
                uint4 v = *(const uint4*)(Mws + (size_t)bz * ((size_t)chi * 512)
                                              + (size_t)(ibl * 64 + ir) * 512 + jbk * 64 + jo);
                *(uint4*)(Mlds + ir * 72 + jo) = v;
            }
            __syncthreads();
            for (int kf = 0; kf < 2; ++kf) {
                bf16x8 bfr[2];
                for (int nt = 0; nt < 2; ++nt) {
                    int y = yg * 32 + nt * 16 + l15;
                    bfr[nt] = *(const bf16x8*)(Ylds + y * 72 + kf * 32 + l4 * 8);
                }
                for (int mt = 0; mt < 2; ++mt) {
                    int ir = xg * 32 + mt * 16 + l15;
                    bf16x8 afr = *(const bf16x8*)(Mlds + ir * 72 + kf * 32 + l4 * 8);
                    accR[mt][0] = __builtin_amdgcn_mfma_f32_16x16x32_bf16(afr, bfr[0], accR[mt][0], 0, 0, 0);
                    accR[mt][1] = __builtin_amdgcn_mfma_f32_16x16x32_bf16(afr, bfr[1], accR[mt][1], 0, 0, 0);
                }
            }
        }
        for (int mt = 0; mt < 2; ++mt)
            for (int nt = 0; nt < 2; ++nt) {
                int y = yg * 32 + nt * 16 + l15;
                int ir = xg * 32 + mt * 16 + l4 * 4;
                unsigned p0 = f2bf(accR[mt][nt][0]) | ((unsigned)f2bf(accR[mt][nt][1]) << 16);
                unsigned p1 = f2bf(accR[mt][nt][2]) | ((unsigned)f2bf(accR[mt][nt][3]) << 16);
                *(uint2*)(Rlds + y * 72 + ir) = make_uint2(p0, p1);
            }
        __syncthreads();
        for (int kf = 0; kf < 2; ++kf) {
            bf16x8 bfr[2];
            for (int nt = 0; nt < 2; ++nt) {
                int y = yg * 32 + nt * 16 + l15;
                bfr[nt] = *(const bf16x8*)(Rlds + y * 72 + kf * 32 + l4 * 8);
            }
            for (int mt = 0; mt < 4; ++mt) {
                int x = xg * 64 + mt * 16 + l15;
                bf16x8 afr = *(const bf16x8*)(Xlds + x * 72 + kf * 32 + l4 * 8);
                acc[mt][0] = __builtin_amdgcn_mfma_f32_16x16x32_bf16(afr, bfr[0], acc[mt][0], 0, 0, 0);
                acc[mt][1] = __builtin_amdgcn_mfma_f32_16x16x32_bf16(afr, bfr[1], acc[mt][1], 0, 0, 0);
            }
        }
    }
    float* op = out + (size_t)bz * 16384;
    for (int mt = 0; mt < 4; ++mt)
        for (int nt = 0; nt < 2; ++nt)
            for (int r = 0; r < 4; ++r) {
                int x = xg * 64 + mt * 16 + l4 * 4 + r;
                int y = yg * 32 + nt * 16 + l15;
                if (first) op[x * 128 + y] = acc[mt][nt][r];
                else       op[x * 128 + y] += acc[mt][nt][r];
            }
}

extern "C" void kernel_launch(void* const* d_in, const int* in_sizes, int n_in,
                              void* d_out, int out_size, void* d_ws, size_t ws_size,
                              hipStream_t stream)
{
    const float* x = (const float*)d_in[0];
    const float* y = (const float*)d_in[1];
    const float* z = (const float*)d_in[2];
    const float* w = (const float*)d_in[3];
    float* out = (float*)d_out;
    char* ws = (char*)d_ws;

    unsigned short* xbf = (unsigned short*)(ws + 0);
    unsigned short* ybf = (unsigned short*)(ws + 524288);
    unsigned short* zbf = (unsigned short*)(ws + 1048576);
    float* a_arr = (float*)(ws + 1572864);
    float* c_arr = (float*)(ws + 2621440);
    float* d_arr = (float*)(ws + 3670016);
    unsigned short* Mws = (unsigned short*)(ws + 3674112);

    size_t avail = (ws_size > 3674112) ? ws_size - 3674112 : 0;
    int chi = 512;                                   // i-rows of M materialized per chunk
    while (chi > 64 && (size_t)chi * 524288 > avail) chi >>= 1;

    hipLaunchKernelGGL(k_cast, dim3(384), dim3(256), 0, stream, x, y, z, xbf, ybf, zbf);
    hipLaunchKernelGGL(k_edge, dim3(136), dim3(256), 0, stream, z, w, a_arr, c_arr, d_arr);

    int nch = 512 / chi;
    for (int c = 0; c < nch; ++c) {
        int i0 = c * chi;
        hipLaunchKernelGGL(k_gemm1, dim3(chi * 8), dim3(512), 73728, stream, zbf, w, Mws, i0, chi);
        hipLaunchKernelGGL(k_fuse, dim3(512), dim3(512), 0, stream, xbf, ybf, Mws,
                           x, y, a_arr, c_arr, d_arr, out, i0, chi / 64, chi, (c == 0) ? 1 : 0);
    }
}

// Round 4
// 543.057 us; speedup vs baseline: 1.1116x; 1.1116x over previous
//
#include <hip/hip_runtime.h>
#include <stdint.h>

// Triaffine: out[b,z,x,y] = sum_{i,j,k} xb[x,i] z[z,k] W[i,k,j] yb[y,j]
// B=4, S=128, D=512.  W: [513][512][513] f32 (i,k,j), elem (i,k,j) at (i*512+k)*513+j.
//
// Decomposition (bias split so all GEMM dims are 512):
//   M[bz,i,j] = sum_k z[bz,k] W[i,k,j]        (i,j < 512)   -- kernel G1, bf16 out
//   per bz:  R[i,y] = sum_j M[i,j] Ybf[y,j]                  -- kernel G2 pass-2
//            out[x,y] = sum_i Xbf[x,i] R[i,y] + u[x]+v[y]+d  -- kernel G2 pass-3
//   a[bz,i] = sum_k z W[i,k,512], c[bz,j] = sum_k z W[512,k,j], d = sum_k z W[512,k,512]

typedef __attribute__((ext_vector_type(8))) short bf16x8;
typedef __attribute__((ext_vector_type(4))) float f32x4;

__device__ __forceinline__ unsigned short f2bf(float f) {
    unsigned int u = __float_as_uint(f);
    u += 0x7fffu + ((u >> 16) & 1u);      // RNE
    return (unsigned short)(u >> 16);
}

__device__ __forceinline__ void gload_lds16(const void* g, void* l) {
    __builtin_amdgcn_global_load_lds((const __attribute__((address_space(1))) void*)g,
                                     (__attribute__((address_space(3))) void*)l, 16, 0, 0);
}

// ---------------- cast x,y,z -> bf16 ----------------
__global__ __launch_bounds__(256) void k_cast(const float* __restrict__ x,
    const float* __restrict__ y, const float* __restrict__ z,
    unsigned short* __restrict__ xbf, unsigned short* __restrict__ ybf,
    unsigned short* __restrict__ zbf)
{
    int t = blockIdx.x * 256 + threadIdx.x;   // 98304 threads, 8 elems each
    int arr = t >> 15;
    int off = (t & 32767) * 8;
    const float* src = (arr == 0) ? x : (arr == 1) ? y : z;
    unsigned short* dst = (arr == 0) ? xbf : (arr == 1) ? ybf : zbf;
    float4 a = *(const float4*)(src + off);
    float4 b = *(const float4*)(src + off + 4);
    uint4 o;
    o.x = f2bf(a.x) | ((unsigned)f2bf(a.y) << 16);
    o.y = f2bf(a.z) | ((unsigned)f2bf(a.w) << 16);
    o.z = f2bf(b.x) | ((unsigned)f2bf(b.y) << 16);
    o.w = f2bf(b.z) | ((unsigned)f2bf(b.w) << 16);
    *(uint4*)(dst + off) = o;
}

// ---------------- bias-edge GEMMs ----------------
__global__ __launch_bounds__(256) void k_edge(const float* __restrict__ z,
    const float* __restrict__ w, float* __restrict__ a_arr,
    float* __restrict__ c_arr, float* __restrict__ d_arr)
{
    __shared__ float Zs[64][33];
    __shared__ float Bs[32][65];
    int t = threadIdx.x;
    int mb = blockIdx.x % 17, bzb = blockIdx.x / 17;
    int tr = t >> 4, tc = t & 15;
    float acc[4][4] = {};
    for (int k0 = 0; k0 < 512; k0 += 32) {
        __syncthreads();
        {   int row = t >> 2, ko = (t & 3) * 8;
            const float* p = z + (bzb * 64 + row) * 512 + k0 + ko;
            float4 v0 = ((const float4*)p)[0], v1 = ((const float4*)p)[1];
            Zs[row][ko + 0] = v0.x; Zs[row][ko + 1] = v0.y; Zs[row][ko + 2] = v0.z; Zs[row][ko + 3] = v0.w;
            Zs[row][ko + 4] = v1.x; Zs[row][ko + 5] = v1.y; Zs[row][ko + 6] = v1.z; Zs[row][ko + 7] = v1.w;
        }
        {   int kr = t >> 3, mo = (t & 7) * 8;
            for (int e = 0; e < 8; ++e) {
                int m = mb * 64 + mo + e;
                float v = 0.f;
                int krow = k0 + kr;
                if (m < 512)        v = w[(m * 512 + krow) * 513 + 512];
                else if (m < 1024)  v = w[(262144 + krow) * 513 + (m - 512)];
                else if (m == 1024) v = w[(262144 + krow) * 513 + 512];
                Bs[kr][mo + e] = v;
            }
        }
        __syncthreads();
        for (int kk = 0; kk < 32; ++kk) {
            float zr[4], br[4];
            for (int r = 0; r < 4; ++r) zr[r] = Zs[tr * 4 + r][kk];
            for (int c = 0; c < 4; ++c) br[c] = Bs[kk][tc * 4 + c];
            for (int r = 0; r < 4; ++r)
                for (int c = 0; c < 4; ++c) acc[r][c] += zr[r] * br[c];
        }
    }
    for (int r = 0; r < 4; ++r)
        for (int c = 0; c < 4; ++c) {
            int bz = bzb * 64 + tr * 4 + r;
            int m = mb * 64 + tc * 4 + c;
            if (m < 512)        a_arr[bz * 512 + m] = acc[r][c];
            else if (m < 1024)  c_arr[bz * 512 + (m - 512)] = acc[r][c];
            else if (m == 1024) d_arr[bz] = acc[r][c];
        }
}

// ---------------- G1: M[bz, i_local, j] = Z(bf16) x W(f32->bf16) ----------------
// BM=512 (all bz; W streamed exactly once), BN=128, BK=32, 16 K-steps.
// 8 waves = 4 bzg x 2 jg; wave tile 128bz x 64j; acc[8][4] = 128 VGPR; 1 WG/CU.
// Per wave-step: 12 ds_read_b128 feed 32 MFMA (was 10 reads for 16 MFMA) --
// halves the LDS-read bytes per FLOP (round-3 diagnosis: LDS-pipe-bound).
// T3/T4 pipeline, fully unrolled; barrier keeps W(ks+2) (8 loads) in flight.
__global__ __launch_bounds__(512, 2) void k_gemm1(const unsigned short* __restrict__ zbf,
    const float* __restrict__ w, unsigned short* __restrict__ Mws,
    int i0, int chi)
{
    extern __shared__ unsigned char smem[];
    unsigned char* Zb0 = smem;                 // [512 rows][32 k] bf16 = 32 KB
    unsigned char* Zb1 = smem + 32768;
    unsigned char* Bb0 = smem + 65536;         // [128 j][32 k] bf16 = 8 KB
    unsigned char* Bb1 = smem + 73728;         // total 81920 B

    int nwg = gridDim.x;
    int cpx = nwg >> 3;
    int bid = blockIdx.x;
    int swz = (bid & 7) * cpx + (bid >> 3);    // XCD swizzle (nwg % 8 == 0)
    int iloc = swz >> 2, jb = swz & 3;
    int j0 = jb * 128;
    int t = threadIdx.x, wid = t >> 6, lane = t & 63;
    int bzg = wid >> 1, jg = wid & 1;
    int l15 = lane & 15, l4 = lane >> 4;

    // Z staging source mapping (pre-swizzled; linear LDS dest => swizzled layout)
    int arow = lane >> 2;                      // row within 16-row block
    int akc  = (lane & 3) ^ ((lane >> 3) & 3); // 16B k-chunk: slot = chunk ^ ((row>>1)&3)
    const unsigned short* zbase = zbf + (size_t)(wid * 64 + arow) * 512 + akc * 8;

    // W staging: thread t -> j = t&127, k-octet kq8 = t>>7 (8 scalar loads, 1 b128 LDS write)
    int jB = t & 127, kq8 = t >> 7;
    const float* wb = w + (size_t)(i0 + iloc) * 262656 + (size_t)(kq8 * 8) * 513 + j0 + jB;
    int bwoff = jB * 64 + (((kq8 >> 1) ^ ((jB >> 1) & 3)) * 16) + 0; // slot = kq8half... see below
    // kq8 covers 8 k => 16 B chunk index = kq8 (each chunk is 8 bf16): slot = kq8 ^ ((jB>>1)&3)
    bwoff = jB * 64 + ((kq8 ^ ((jB >> 1) & 3)) * 16);

    // fragment read offsets (swizzled); row stride 64 B
    int aoff = (bzg * 128 + l15) * 64 + ((l4 ^ ((l15 >> 1) & 3)) * 16);
    int boff = (jg * 64 + l15) * 64 + ((l4 ^ ((l15 >> 1) & 3)) * 16);

    f32x4 acc[8][4];
    #pragma unroll
    for (int mt = 0; mt < 8; ++mt)
        #pragma unroll
        for (int nt = 0; nt < 4; ++nt) acc[mt][nt] = (f32x4){0.f, 0.f, 0.f, 0.f};

    float wr[2][8];

    // ---- prologue: Z(0) glds, W(0) and W(1) reg loads, pack W(0) ----
    #pragma unroll
    for (int q = 0; q < 4; ++q)
        gload_lds16(zbase + q * 8192, Zb0 + wid * 4096 + q * 1024);
    {
        #pragma unroll
        for (int e = 0; e < 8; ++e) wr[0][e] = wb[(size_t)e * 513];
        const float* wp = wb + (size_t)32 * 513;
        #pragma unroll
        for (int e = 0; e < 8; ++e) wr[1][e] = wp[(size_t)e * 513];
        // pack W(0): compiler inserts counted vmcnt (drains Z(0)+W(0), leaves W(1))
        uint4 pk;
        pk.x = f2bf(wr[0][0]) | ((unsigned)f2bf(wr[0][1]) << 16);
        pk.y = f2bf(wr[0][2]) | ((unsigned)f2bf(wr[0][3]) << 16);
        pk.z = f2bf(wr[0][4]) | ((unsigned)f2bf(wr[0][5]) << 16);
        pk.w = f2bf(wr[0][6]) | ((unsigned)f2bf(wr[0][7]) << 16);
        *(uint4*)(Bb0 + bwoff) = pk;
    }
    asm volatile("s_waitcnt lgkmcnt(0)" ::: "memory");
    __builtin_amdgcn_s_barrier();
    __builtin_amdgcn_sched_barrier(0);

    #pragma unroll
    for (int ks = 0; ks < 16; ++ks) {
        const int cur = ks & 1;
        unsigned char* Zcur  = cur ? Zb1 : Zb0;
        unsigned char* Znext = cur ? Zb0 : Zb1;
        unsigned char* Bcur  = cur ? Bb1 : Bb0;
        unsigned char* Bnext = cur ? Bb0 : Bb1;

        // 1. issue Z(ks+1) -> Znext
        if (ks < 15) {
            #pragma unroll
            for (int q = 0; q < 4; ++q)
                gload_lds16(zbase + (ks + 1) * 32 + q * 8192, Znext + wid * 4096 + q * 1024);
        }
        // 2. issue W(ks+2) -> wr[cur] (2-deep prefetch)
        if (ks < 14) {
            const float* wp = wb + (size_t)(ks + 2) * 32 * 513;
            #pragma unroll
            for (int e = 0; e < 8; ++e) wr[cur][e] = wp[(size_t)e * 513];
        }
        // 3. compute on current buffers: 4 B-frags + 8x(1 A-frag, 4 MFMA)
        bf16x8 bfr[4];
        #pragma unroll
        for (int nt = 0; nt < 4; ++nt)
            bfr[nt] = *(const bf16x8*)(Bcur + boff + nt * 1024);
        #pragma unroll
        for (int mt = 0; mt < 8; ++mt) {
            bf16x8 afr = *(const bf16x8*)(Zcur + aoff + mt * 1024);
            #pragma unroll
            for (int nt = 0; nt < 4; ++nt)
                acc[mt][nt] = __builtin_amdgcn_mfma_f32_16x16x32_bf16(afr, bfr[nt], acc[mt][nt], 0, 0, 0);
        }
        // 4. pack W(ks+1) -> Bnext (compiler's counted wait drains only W(ks+1))
        if (ks < 15) {
            uint4 pk;
            pk.x = f2bf(wr[cur ^ 1][0]) | ((unsigned)f2bf(wr[cur ^ 1][1]) << 16);
            pk.y = f2bf(wr[cur ^ 1][2]) | ((unsigned)f2bf(wr[cur ^ 1][3]) << 16);
            pk.z = f2bf(wr[cur ^ 1][4]) | ((unsigned)f2bf(wr[cur ^ 1][5]) << 16);
            pk.w = f2bf(wr[cur ^ 1][6]) | ((unsigned)f2bf(wr[cur ^ 1][7]) << 16);
            *(uint4*)(Bnext + bwoff) = pk;
        }
        // 5. counted-vmcnt barrier: drain Z(ks+1)+ds_write, keep W(ks+2) (8) in flight
        if (ks < 14) {
            asm volatile("s_waitcnt vmcnt(8) lgkmcnt(0)" ::: "memory");
        } else if (ks == 14) {
            asm volatile("s_waitcnt vmcnt(0) lgkmcnt(0)" ::: "memory");
        }
        if (ks < 15) {
            __builtin_amdgcn_s_barrier();
            __builtin_amdgcn_sched_barrier(0);
        }
    }

    // ---- epilogue: store M[bz][iloc][j] bf16 ----
    size_t mrow = (size_t)chi * 512;
    #pragma unroll
    for (int mt = 0; mt < 8; ++mt)
        #pragma unroll
        for (int nt = 0; nt < 4; ++nt)
            #pragma unroll
            for (int r = 0; r < 4; ++r) {
                int bz = bzg * 128 + mt * 16 + l4 * 4 + r;
                int j  = j0 + jg * 64 + nt * 16 + l15;
                Mws[(size_t)bz * mrow + (size_t)iloc * 512 + j] = f2bf(acc[mt][nt][r]);
            }
}

// ---------------- G2: per-bz fused  R = M x Y^T ;  out += X x R  (+bias terms) ----------------
__global__ __launch_bounds__(512) void k_fuse(const unsigned short* __restrict__ xbf,
    const unsigned short* __restrict__ ybf, const unsigned short* __restrict__ Mws,
    const float* __restrict__ xf, const float* __restrict__ yf,
    const float* __restrict__ a_arr, const float* __restrict__ c_arr,
    const float* __restrict__ d_arr, float* __restrict__ out,
    int i0, int nib, int chi, int first)
{
    __shared__ unsigned short Xlds[128 * 72];   // [x][i]  stride 72 ush = 144 B
    __shared__ unsigned short Ylds[128 * 72];   // [y][j]
    __shared__ unsigned short Mlds[64 * 72];    // [i][j]
    __shared__ unsigned short Rlds[128 * 72];   // [y][i]
    int bid = blockIdx.x;
    int bz = (bid & 7) * 64 + (bid >> 3);       // XCD swizzle
    int b = bz >> 7;
    int t = threadIdx.x;
    int wid = t >> 6, lane = t & 63;
    int l15 = lane & 15, l4 = lane >> 4;
    int xg = wid >> 2, yg = wid & 3;

    f32x4 acc[4][2];
    if (first) {
        float* part = (float*)Xlds;             // 512 f32
        float* uv = (float*)Ylds;               // u[128], v[128]
        int xr = t & 127, q = t >> 7;
        {   const float* xp = xf + (size_t)(b * 128 + xr) * 512 + q * 128;
            const float* ap = a_arr + bz * 512 + q * 128;
            float s = 0.f;
            for (int ii = 0; ii < 128; ++ii) s += xp[ii] * ap[ii];
            part[q * 128 + xr] = s;
        }
        __syncthreads();
        if (t < 128) uv[t] = part[t] + part[128 + t] + part[256 + t] + part[384 + t];
        __syncthreads();
        {   const float* yp = yf + (size_t)(b * 128 + xr) * 512 + q * 128;
            const float* cp = c_arr + bz * 512 + q * 128;
            float s = 0.f;
            for (int ii = 0; ii < 128; ++ii) s += yp[ii] * cp[ii];
            part[q * 128 + xr] = s;
        }
        __syncthreads();
        if (t < 128) uv[128 + t] = part[t] + part[128 + t] + part[256 + t] + part[384 + t];
        __syncthreads();
        float dv = d_arr[bz];
        for (int mt = 0; mt < 4; ++mt)
            for (int nt = 0; nt < 2; ++nt) {
                int y = yg * 32 + nt * 16 + l15;
                for (int r = 0; r < 4; ++r) {
                    int x = xg * 64 + mt * 16 + l4 * 4 + r;
                    acc[mt][nt][r] = uv[x] + uv[128 + y] + dv;
                }
            }
    } else {
        for (int mt = 0; mt < 4; ++mt) for (int nt = 0; nt < 2; ++nt) acc[mt][nt] = (f32x4){0.f,0.f,0.f,0.f};
    }

    for (int ibl = 0; ibl < nib; ++ibl) {
        __syncthreads();
        {   int xr = t >> 2, io = (t & 3) * 16;
            const uint4* src = (const uint4*)(xbf + (size_t)(b * 128 + xr) * 512 + i0 + ibl * 64 + io);
            uint4 v0 = src[0], v1 = src[1];
            uint4* dst = (uint4*)(Xlds + xr * 72 + io);
            dst[0] = v0; dst[1] = v1;
        }
        f32x4 accR[2][2];
        for (int mt = 0; mt < 2; ++mt) for (int nt = 0; nt < 2; ++nt) accR[mt][nt] = (f32x4){0.f,0.f,0.f,0.f};

        for (int jbk = 0; jbk < 8; ++jbk) {
            __syncthreads();
            {   int yr = t >> 2, jo = (t & 3) * 16;
                const uint4* src = (const uint4*)(ybf + (size_t)(b * 128 + yr) * 512 + jbk * 64 + jo);
                uint4 v0 = src[0], v1 = src[1];
                uint4* dst = (uint4*)(Ylds + yr * 72 + jo);
                dst[0] = v0; dst[1] = v1;
            }
            {   int ir = t >> 3, jo = (t & 7) * 8;
                uint4 v = *(const uint4*)(Mws + (size_t)bz * ((size_t)chi * 512)
                                              + (size_t)(ibl * 64 + ir) * 512 + jbk * 64 + jo);
                *(uint4*)(Mlds + ir * 72 + jo) = v;
            }
            __syncthreads();
            for (int kf = 0; kf < 2; ++kf) {
                bf16x8 bfr[2];
                for (int nt = 0; nt < 2; ++nt) {
                    int y = yg * 32 + nt * 16 + l15;
                    bfr[nt] = *(const bf16x8*)(Ylds + y * 72 + kf * 32 + l4 * 8);
                }
                for (int mt = 0; mt < 2; ++mt) {
                    int ir = xg * 32 + mt * 16 + l15;
                    bf16x8 afr = *(const bf16x8*)(Mlds + ir * 72 + kf * 32 + l4 * 8);
                    accR[mt][0] = __builtin_amdgcn_mfma_f32_16x16x32_bf16(afr, bfr[0], accR[mt][0], 0, 0, 0);
                    accR[mt][1] = __builtin_amdgcn_mfma_f32_16x16x32_bf16(afr, bfr[1], accR[mt][1], 0, 0, 0);
                }
            }
        }
        for (int mt = 0; mt < 2; ++mt)
            for (int nt = 0; nt < 2; ++nt) {
                int y = yg * 32 + nt * 16 + l15;
                int ir = xg * 32 + mt * 16 + l4 * 4;
                unsigned p0 = f2bf(accR[mt][nt][0]) | ((unsigned)f2bf(accR[mt][nt][1]) << 16);
                unsigned p1 = f2bf(accR[mt][nt][2]) | ((unsigned)f2bf(accR[mt][nt][3]) << 16);
                *(uint2*)(Rlds + y * 72 + ir) = make_uint2(p0, p1);
            }
        __syncthreads();
        for (int kf = 0; kf < 2; ++kf) {
            bf16x8 bfr[2];
            for (int nt = 0; nt < 2; ++nt) {
                int y = yg * 32 + nt * 16 + l15;
                bfr[nt] = *(const bf16x8*)(Rlds + y * 72 + kf * 32 + l4 * 8);
            }
            for (int mt = 0; mt < 4; ++mt) {
                int x = xg * 64 + mt * 16 + l15;
                bf16x8 afr = *(const bf16x8*)(Xlds + x * 72 + kf * 32 + l4 * 8);
                acc[mt][0] = __builtin_amdgcn_mfma_f32_16x16x32_bf16(afr, bfr[0], acc[mt][0], 0, 0, 0);
                acc[mt][1] = __builtin_amdgcn_mfma_f32_16x16x32_bf16(afr, bfr[1], acc[mt][1], 0, 0, 0);
            }
        }
    }
    float* op = out + (size_t)bz * 16384;
    for (int mt = 0; mt < 4; ++mt)
        for (int nt = 0; nt < 2; ++nt)
            for (int r = 0; r < 4; ++r) {
                int x = xg * 64 + mt * 16 + l4 * 4 + r;
                int y = yg * 32 + nt * 16 + l15;
                if (first) op[x * 128 + y] = acc[mt][nt][r];
                else       op[x * 128 + y] += acc[mt][nt][r];
            }
}

extern "C" void kernel_launch(void* const* d_in, const int* in_sizes, int n_in,
                              void* d_out, int out_size, void* d_ws, size_t ws_size,
                              hipStream_t stream)
{
    const float* x = (const float*)d_in[0];
    const float* y = (const float*)d_in[1];
    const float* z = (const float*)d_in[2];
    const float* w = (const float*)d_in[3];
    float* out = (float*)d_out;
    char* ws = (char*)d_ws;

    unsigned short* xbf = (unsigned short*)(ws + 0);
    unsigned short* ybf = (unsigned short*)(ws + 524288);
    unsigned short* zbf = (unsigned short*)(ws + 1048576);
    float* a_arr = (float*)(ws + 1572864);
    float* c_arr = (float*)(ws + 2621440);
    float* d_arr = (float*)(ws + 3670016);
    unsigned short* Mws = (unsigned short*)(ws + 3674112);

    size_t avail = (ws_size > 3674112) ? ws_size - 3674112 : 0;
    int chi = 512;                                   // i-rows of M materialized per chunk
    while (chi > 64 && (size_t)chi * 524288 > avail) chi >>= 1;

    hipLaunchKernelGGL(k_cast, dim3(384), dim3(256), 0, stream, x, y, z, xbf, ybf, zbf);
    hipLaunchKernelGGL(k_edge, dim3(136), dim3(256), 0, stream, z, w, a_arr, c_arr, d_arr);

    int nch = 512 / chi;
    for (int c = 0; c < nch; ++c) {
        int i0 = c * chi;
        hipLaunchKernelGGL(k_gemm1, dim3(chi * 4), dim3(512), 81920, stream, zbf, w, Mws, i0, chi);
        hipLaunchKernelGGL(k_fuse, dim3(512), dim3(512), 0, stream, xbf, ybf, Mws,
                           x, y, a_arr, c_arr, d_arr, out, i0, chi / 64, chi, (c == 0) ? 1 : 0);
    }
}

// Round 5
// 484.674 us; speedup vs baseline: 1.2455x; 1.1205x over previous
//
#include <hip/hip_runtime.h>
#include <stdint.h>

// Triaffine: out[b,z,x,y] = sum_{i,j,k} xb[x,i] z[z,k] W[i,k,j] yb[y,j]
// B=4, S=128, D=512.  W: [513][512][513] f32 (i,k,j), elem (i,k,j) at (i*512+k)*513+j.
//
// Decomposition (bias split so all GEMM dims are 512):
//   M[bz,i,j] = sum_k z[bz,k] W[i,k,j]        (i,j < 512)   -- kernel G1, bf16 out
//   per bz:  R[i,y] = sum_j M[i,j] Ybf[y,j]                  -- kernel G2 pass-2
//            out[x,y] = sum_i Xbf[x,i] R[i,y] + u[x]+v[y]+d  -- kernel G2 pass-3
//   a[bz,i] = sum_k z W[i,k,512], c[bz,j] = sum_k z W[512,k,j], d = sum_k z W[512,k,512]

typedef __attribute__((ext_vector_type(8))) short bf16x8;
typedef __attribute__((ext_vector_type(4))) float f32x4;

__device__ __forceinline__ unsigned short f2bf(float f) {
    unsigned int u = __float_as_uint(f);
    u += 0x7fffu + ((u >> 16) & 1u);      // RNE
    return (unsigned short)(u >> 16);
}

__device__ __forceinline__ void gload_lds16(const void* g, void* l) {
    __builtin_amdgcn_global_load_lds((const __attribute__((address_space(1))) void*)g,
                                     (__attribute__((address_space(3))) void*)l, 16, 0, 0);
}

// ---------------- cast x,y,z -> bf16 ----------------
__global__ __launch_bounds__(256) void k_cast(const float* __restrict__ x,
    const float* __restrict__ y, const float* __restrict__ z,
    unsigned short* __restrict__ xbf, unsigned short* __restrict__ ybf,
    unsigned short* __restrict__ zbf)
{
    int t = blockIdx.x * 256 + threadIdx.x;   // 98304 threads, 8 elems each
    int arr = t >> 15;
    int off = (t & 32767) * 8;
    const float* src = (arr == 0) ? x : (arr == 1) ? y : z;
    unsigned short* dst = (arr == 0) ? xbf : (arr == 1) ? ybf : zbf;
    float4 a = *(const float4*)(src + off);
    float4 b = *(const float4*)(src + off + 4);
    uint4 o;
    o.x = f2bf(a.x) | ((unsigned)f2bf(a.y) << 16);
    o.y = f2bf(a.z) | ((unsigned)f2bf(a.w) << 16);
    o.z = f2bf(b.x) | ((unsigned)f2bf(b.y) << 16);
    o.w = f2bf(b.z) | ((unsigned)f2bf(b.w) << 16);
    *(uint4*)(dst + off) = o;
}

// ---------------- bias-edge GEMMs ----------------
__global__ __launch_bounds__(256) void k_edge(const float* __restrict__ z,
    const float* __restrict__ w, float* __restrict__ a_arr,
    float* __restrict__ c_arr, float* __restrict__ d_arr)
{
    __shared__ float Zs[64][33];
    __shared__ float Bs[32][65];
    int t = threadIdx.x;
    int mb = blockIdx.x % 17, bzb = blockIdx.x / 17;
    int tr = t >> 4, tc = t & 15;
    float acc[4][4] = {};
    for (int k0 = 0; k0 < 512; k0 += 32) {
        __syncthreads();
        {   int row = t >> 2, ko = (t & 3) * 8;
            const float* p = z + (bzb * 64 + row) * 512 + k0 + ko;
            float4 v0 = ((const float4*)p)[0], v1 = ((const float4*)p)[1];
            Zs[row][ko + 0] = v0.x; Zs[row][ko + 1] = v0.y; Zs[row][ko + 2] = v0.z; Zs[row][ko + 3] = v0.w;
            Zs[row][ko + 4] = v1.x; Zs[row][ko + 5] = v1.y; Zs[row][ko + 6] = v1.z; Zs[row][ko + 7] = v1.w;
        }
        {   int kr = t >> 3, mo = (t & 7) * 8;
            for (int e = 0; e < 8; ++e) {
                int m = mb * 64 + mo + e;
                float v = 0.f;
                int krow = k0 + kr;
                if (m < 512)        v = w[(m * 512 + krow) * 513 + 512];
                else if (m < 1024)  v = w[(262144 + krow) * 513 + (m - 512)];
                else if (m == 1024) v = w[(262144 + krow) * 513 + 512];
                Bs[kr][mo + e] = v;
            }
        }
        __syncthreads();
        for (int kk = 0; kk < 32; ++kk) {
            float zr[4], br[4];
            for (int r = 0; r < 4; ++r) zr[r] = Zs[tr * 4 + r][kk];
            for (int c = 0; c < 4; ++c) br[c] = Bs[kk][tc * 4 + c];
            for (int r = 0; r < 4; ++r)
                for (int c = 0; c < 4; ++c) acc[r][c] += zr[r] * br[c];
        }
    }
    for (int r = 0; r < 4; ++r)
        for (int c = 0; c < 4; ++c) {
            int bz = bzb * 64 + tr * 4 + r;
            int m = mb * 64 + tc * 4 + c;
            if (m < 512)        a_arr[bz * 512 + m] = acc[r][c];
            else if (m < 1024)  c_arr[bz * 512 + (m - 512)] = acc[r][c];
            else if (m == 1024) d_arr[bz] = acc[r][c];
        }
}

// ---------------- G1: M[bz, i_local, j] = Z(bf16) x W(f32->bf16) ----------------
// BM=512 (all bz; W streamed exactly once), BN=128, BK=32, 16 K-steps.
// 8 waves = 4 bzg x 2 jg; wave tile 128bz x 64j; acc[8][4].
__global__ __launch_bounds__(512, 2) void k_gemm1(const unsigned short* __restrict__ zbf,
    const float* __restrict__ w, unsigned short* __restrict__ Mws,
    int i0, int chi)
{
    extern __shared__ unsigned char smem[];
    unsigned char* Zb0 = smem;                 // [512 rows][32 k] bf16 = 32 KB
    unsigned char* Zb1 = smem + 32768;
    unsigned char* Bb0 = smem + 65536;         // [128 j][32 k] bf16 = 8 KB
    unsigned char* Bb1 = smem + 73728;         // total 81920 B

    int nwg = gridDim.x;
    int cpx = nwg >> 3;
    int bid = blockIdx.x;
    int swz = (bid & 7) * cpx + (bid >> 3);    // XCD swizzle (nwg % 8 == 0)
    int iloc = swz >> 2, jb = swz & 3;
    int j0 = jb * 128;
    int t = threadIdx.x, wid = t >> 6, lane = t & 63;
    int bzg = wid >> 1, jg = wid & 1;
    int l15 = lane & 15, l4 = lane >> 4;

    int arow = lane >> 2;
    int akc  = (lane & 3) ^ ((lane >> 3) & 3);
    const unsigned short* zbase = zbf + (size_t)(wid * 64 + arow) * 512 + akc * 8;

    int jB = t & 127, kq8 = t >> 7;
    const float* wb = w + (size_t)(i0 + iloc) * 262656 + (size_t)(kq8 * 8) * 513 + j0 + jB;
    int bwoff = jB * 64 + ((kq8 ^ ((jB >> 1) & 3)) * 16);

    int aoff = (bzg * 128 + l15) * 64 + ((l4 ^ ((l15 >> 1) & 3)) * 16);
    int boff = (jg * 64 + l15) * 64 + ((l4 ^ ((l15 >> 1) & 3)) * 16);

    f32x4 acc[8][4];
    #pragma unroll
    for (int mt = 0; mt < 8; ++mt)
        #pragma unroll
        for (int nt = 0; nt < 4; ++nt) acc[mt][nt] = (f32x4){0.f, 0.f, 0.f, 0.f};

    float wr[2][8];

    #pragma unroll
    for (int q = 0; q < 4; ++q)
        gload_lds16(zbase + q * 8192, Zb0 + wid * 4096 + q * 1024);
    {
        #pragma unroll
        for (int e = 0; e < 8; ++e) wr[0][e] = wb[(size_t)e * 513];
        const float* wp = wb + (size_t)32 * 513;
        #pragma unroll
        for (int e = 0; e < 8; ++e) wr[1][e] = wp[(size_t)e * 513];
        uint4 pk;
        pk.x = f2bf(wr[0][0]) | ((unsigned)f2bf(wr[0][1]) << 16);
        pk.y = f2bf(wr[0][2]) | ((unsigned)f2bf(wr[0][3]) << 16);
        pk.z = f2bf(wr[0][4]) | ((unsigned)f2bf(wr[0][5]) << 16);
        pk.w = f2bf(wr[0][6]) | ((unsigned)f2bf(wr[0][7]) << 16);
        *(uint4*)(Bb0 + bwoff) = pk;
    }
    asm volatile("s_waitcnt lgkmcnt(0)" ::: "memory");
    __builtin_amdgcn_s_barrier();
    __builtin_amdgcn_sched_barrier(0);

    #pragma unroll
    for (int ks = 0; ks < 16; ++ks) {
        const int cur = ks & 1;
        unsigned char* Zcur  = cur ? Zb1 : Zb0;
        unsigned char* Znext = cur ? Zb0 : Zb1;
        unsigned char* Bcur  = cur ? Bb1 : Bb0;
        unsigned char* Bnext = cur ? Bb0 : Bb1;

        if (ks < 15) {
            #pragma unroll
            for (int q = 0; q < 4; ++q)
                gload_lds16(zbase + (ks + 1) * 32 + q * 8192, Znext + wid * 4096 + q * 1024);
        }
        if (ks < 14) {
            const float* wp = wb + (size_t)(ks + 2) * 32 * 513;
            #pragma unroll
            for (int e = 0; e < 8; ++e) wr[cur][e] = wp[(size_t)e * 513];
        }
        bf16x8 bfr[4];
        #pragma unroll
        for (int nt = 0; nt < 4; ++nt)
            bfr[nt] = *(const bf16x8*)(Bcur + boff + nt * 1024);
        #pragma unroll
        for (int mt = 0; mt < 8; ++mt) {
            bf16x8 afr = *(const bf16x8*)(Zcur + aoff + mt * 1024);
            #pragma unroll
            for (int nt = 0; nt < 4; ++nt)
                acc[mt][nt] = __builtin_amdgcn_mfma_f32_16x16x32_bf16(afr, bfr[nt], acc[mt][nt], 0, 0, 0);
        }
        if (ks < 15) {
            uint4 pk;
            pk.x = f2bf(wr[cur ^ 1][0]) | ((unsigned)f2bf(wr[cur ^ 1][1]) << 16);
            pk.y = f2bf(wr[cur ^ 1][2]) | ((unsigned)f2bf(wr[cur ^ 1][3]) << 16);
            pk.z = f2bf(wr[cur ^ 1][4]) | ((unsigned)f2bf(wr[cur ^ 1][5]) << 16);
            pk.w = f2bf(wr[cur ^ 1][6]) | ((unsigned)f2bf(wr[cur ^ 1][7]) << 16);
            *(uint4*)(Bnext + bwoff) = pk;
        }
        if (ks < 14) {
            asm volatile("s_waitcnt vmcnt(8) lgkmcnt(0)" ::: "memory");
        } else if (ks == 14) {
            asm volatile("s_waitcnt vmcnt(0) lgkmcnt(0)" ::: "memory");
        }
        if (ks < 15) {
            __builtin_amdgcn_s_barrier();
            __builtin_amdgcn_sched_barrier(0);
        }
    }

    size_t mrow = (size_t)chi * 512;
    #pragma unroll
    for (int mt = 0; mt < 8; ++mt)
        #pragma unroll
        for (int nt = 0; nt < 4; ++nt)
            #pragma unroll
            for (int r = 0; r < 4; ++r) {
                int bz = bzg * 128 + mt * 16 + l4 * 4 + r;
                int j  = j0 + jg * 64 + nt * 16 + l15;
                Mws[(size_t)bz * mrow + (size_t)iloc * 512 + j] = f2bf(acc[mt][nt][r]);
            }
}

// ---------------- G2 v2: per-bz fused  R = M x Y^T ;  out += X x R  (+bias) ----------------
// 8 waves as 4 groups x 2 groups; iblock IB=128 (nib = chi/128 iblocks), j-chunk 64.
// Pass-2 wave tile 32i x 64y (accR[2][4]); pass-3 wave tile 32x x 64y (acc[2][4]).
// LDS 128 KB: Y dbuf 2x16K [128y][64j], M dbuf 2x16K [128i][64j], X 32K [128x][128i],
// R 32K [128y][128i].  Swizzles: 128B rows: slot=chunk^(row&7); 256B rows: ^(row&15).
// Pipeline: stage(next) via gload_lds -> compute(cur) -> vmcnt(0) barrier (1/step).
__global__ __launch_bounds__(512, 2) void k_fuse(const unsigned short* __restrict__ xbf,
    const unsigned short* __restrict__ ybf, const unsigned short* __restrict__ Mws,
    const float* __restrict__ xf, const float* __restrict__ yf,
    const float* __restrict__ a_arr, const float* __restrict__ c_arr,
    const float* __restrict__ d_arr, float* __restrict__ out,
    int i0, int nib, int chi, int first)
{
    extern __shared__ unsigned char smem[];
    unsigned char* Yb = smem;                  // 2 x 16384
    unsigned char* Mb = smem + 32768;          // 2 x 16384
    unsigned char* Xl = smem + 65536;          // 32768
    unsigned char* Rl = smem + 98304;          // 32768   (total 131072)

    int bid = blockIdx.x;
    int bz = (bid & 7) * 64 + (bid >> 3);      // XCD swizzle (512 = 8*64)
    int b = bz >> 7;
    int t = threadIdx.x;
    int wid = t >> 6, lane = t & 63;
    int l15 = lane & 15, l4 = lane >> 4;
    int g4 = wid >> 1, g2 = wid & 1;           // 4-group (i / x), 2-group (y)

    // staging index helpers
    int srow = t >> 3;                         // 0..63 (row within 64-row half)
    int sj16 = (t & 7) ^ ((t >> 3) & 7);       // pre-swizzled 16B chunk for 128B rows
    int xrow = t >> 4;                         // 0..31
    int xi16 = (t & 15) ^ ((t >> 4) & 15);     // pre-swizzled chunk for 256B rows
    size_t bzoff = (size_t)bz * ((size_t)chi * 512);
    const unsigned short* ybase = ybf + (size_t)(b * 128) * 512;
    const unsigned short* xbase = xbf + (size_t)(b * 128) * 512;

    f32x4 acc[2][4];
    // ---- prologue: stage step 0, then bias init ----
    gload_lds16(ybase + (size_t)srow * 512 + sj16 * 8, Yb + t * 16);
    gload_lds16(ybase + (size_t)(64 + srow) * 512 + sj16 * 8, Yb + 8192 + t * 16);
    gload_lds16(Mws + bzoff + (size_t)srow * 512 + sj16 * 8, Mb + t * 16);
    gload_lds16(Mws + bzoff + (size_t)(64 + srow) * 512 + sj16 * 8, Mb + 8192 + t * 16);

    if (first) {
        float* part = (float*)Rl;              // 512 f32
        float* uv = (float*)(Rl + 4096);       // 256 f32
        int xr = t & 127, q = t >> 7;
        {   const float* xp = xf + (size_t)(b * 128 + xr) * 512 + q * 128;
            const float* ap = a_arr + bz * 512 + q * 128;
            float s = 0.f;
            for (int ii = 0; ii < 128; ++ii) s += xp[ii] * ap[ii];
            part[q * 128 + xr] = s;
        }
        __syncthreads();
        if (t < 128) uv[t] = part[t] + part[128 + t] + part[256 + t] + part[384 + t];
        __syncthreads();
        {   const float* yp = yf + (size_t)(b * 128 + xr) * 512 + q * 128;
            const float* cp = c_arr + bz * 512 + q * 128;
            float s = 0.f;
            for (int ii = 0; ii < 128; ++ii) s += yp[ii] * cp[ii];
            part[q * 128 + xr] = s;
        }
        __syncthreads();
        if (t < 128) uv[128 + t] = part[t] + part[128 + t] + part[256 + t] + part[384 + t];
        __syncthreads();
        float dv = d_arr[bz];
        #pragma unroll
        for (int mt = 0; mt < 2; ++mt)
            #pragma unroll
            for (int nt = 0; nt < 4; ++nt) {
                int y = g2 * 64 + nt * 16 + l15;
                #pragma unroll
                for (int r = 0; r < 4; ++r) {
                    int x = g4 * 32 + mt * 16 + l4 * 4 + r;
                    acc[mt][nt][r] = uv[x] + uv[128 + y] + dv;
                }
            }
    } else {
        #pragma unroll
        for (int mt = 0; mt < 2; ++mt)
            #pragma unroll
            for (int nt = 0; nt < 4; ++nt) acc[mt][nt] = (f32x4){0.f,0.f,0.f,0.f};
    }
    asm volatile("s_waitcnt vmcnt(0) lgkmcnt(0)" ::: "memory");
    __builtin_amdgcn_s_barrier();
    __builtin_amdgcn_sched_barrier(0);

    int NF = nib * 8;
    for (int ibl = 0; ibl < nib; ++ibl) {
        f32x4 accR[2][4];
        #pragma unroll
        for (int mt = 0; mt < 2; ++mt)
            #pragma unroll
            for (int nt = 0; nt < 4; ++nt) accR[mt][nt] = (f32x4){0.f,0.f,0.f,0.f};

        #pragma unroll
        for (int s = 0; s < 8; ++s) {
            int f = ibl * 8 + s;
            const int cur = s & 1;
            unsigned char* Ycur = Yb + cur * 16384;
            unsigned char* Mcur = Mb + cur * 16384;
            unsigned char* Ynxt = Yb + (cur ^ 1) * 16384;
            unsigned char* Mnxt = Mb + (cur ^ 1) * 16384;

            // A. stage next-step Y/M
            if (f + 1 < NF) {
                int jn = ((f + 1) & 7) * 64;
                int rn = ((f + 1) >> 3) * 128;
                gload_lds16(ybase + (size_t)srow * 512 + jn + sj16 * 8, Ynxt + t * 16);
                gload_lds16(ybase + (size_t)(64 + srow) * 512 + jn + sj16 * 8, Ynxt + 8192 + t * 16);
                gload_lds16(Mws + bzoff + (size_t)(rn + srow) * 512 + jn + sj16 * 8, Mnxt + t * 16);
                gload_lds16(Mws + bzoff + (size_t)(rn + 64 + srow) * 512 + jn + sj16 * 8, Mnxt + 8192 + t * 16);
            }
            // B. stage X(ibl) at s==0 (X region free since pass-3(ibl-1) ended with barrier)
            if (s == 0) {
                #pragma unroll
                for (int q = 0; q < 4; ++q)
                    gload_lds16(xbase + (size_t)(q * 32 + xrow) * 512 + i0 + ibl * 128 + xi16 * 8,
                                Xl + q * 8192 + t * 16);
            }
            // C. compute pass-2 step: accR += M-tile x Y-tile^T
            #pragma unroll
            for (int kf = 0; kf < 2; ++kf) {
                bf16x8 bfr[4], afr[2];
                #pragma unroll
                for (int nt = 0; nt < 4; ++nt) {
                    int y = g2 * 64 + nt * 16 + l15;
                    bfr[nt] = *(const bf16x8*)(Ycur + y * 128 + (((kf * 4 + l4) ^ (y & 7)) * 16));
                }
                #pragma unroll
                for (int mt = 0; mt < 2; ++mt) {
                    int ir = g4 * 32 + mt * 16 + l15;
                    afr[mt] = *(const bf16x8*)(Mcur + ir * 128 + (((kf * 4 + l4) ^ (ir & 7)) * 16));
                }
                #pragma unroll
                for (int mt = 0; mt < 2; ++mt)
                    #pragma unroll
                    for (int nt = 0; nt < 4; ++nt)
                        accR[mt][nt] = __builtin_amdgcn_mfma_f32_16x16x32_bf16(afr[mt], bfr[nt], accR[mt][nt], 0, 0, 0);
            }
            // D. single barrier per step
            asm volatile("s_waitcnt vmcnt(0) lgkmcnt(0)" ::: "memory");
            __builtin_amdgcn_s_barrier();
            __builtin_amdgcn_sched_barrier(0);
        }

        // write accR -> Rl [y][i] bf16 (swizzled 256B rows)
        #pragma unroll
        for (int mt = 0; mt < 2; ++mt)
            #pragma unroll
            for (int nt = 0; nt < 4; ++nt) {
                int y = g2 * 64 + nt * 16 + l15;
                int ib = g4 * 32 + mt * 16 + l4 * 4;
                unsigned p0 = f2bf(accR[mt][nt][0]) | ((unsigned)f2bf(accR[mt][nt][1]) << 16);
                unsigned p1 = f2bf(accR[mt][nt][2]) | ((unsigned)f2bf(accR[mt][nt][3]) << 16);
                int byte = y * 256 + (((ib >> 3) ^ (y & 15)) * 16) + ((ib & 4) << 1);
                *(uint2*)(Rl + byte) = make_uint2(p0, p1);
            }
        asm volatile("s_waitcnt lgkmcnt(0)" ::: "memory");
        __builtin_amdgcn_s_barrier();
        __builtin_amdgcn_sched_barrier(0);

        // pass-3: acc += X-tile x R-tile^T  (K = 128 i)
        #pragma unroll
        for (int kf = 0; kf < 4; ++kf) {
            bf16x8 bfr[4], afr[2];
            #pragma unroll
            for (int nt = 0; nt < 4; ++nt) {
                int y = g2 * 64 + nt * 16 + l15;
                bfr[nt] = *(const bf16x8*)(Rl + y * 256 + (((kf * 4 + l4) ^ (y & 15)) * 16));
            }
            #pragma unroll
            for (int mt = 0; mt < 2; ++mt) {
                int xr = g4 * 32 + mt * 16 + l15;
                afr[mt] = *(const bf16x8*)(Xl + xr * 256 + (((kf * 4 + l4) ^ (xr & 15)) * 16));
            }
            #pragma unroll
            for (int mt = 0; mt < 2; ++mt)
                #pragma unroll
                for (int nt = 0; nt < 4; ++nt)
                    acc[mt][nt] = __builtin_amdgcn_mfma_f32_16x16x32_bf16(afr[mt], bfr[nt], acc[mt][nt], 0, 0, 0);
        }
        // protect X and R regions before next iblock's staging / R overwrite
        if (ibl + 1 < nib) {
            asm volatile("s_waitcnt lgkmcnt(0)" ::: "memory");
            __builtin_amdgcn_s_barrier();
            __builtin_amdgcn_sched_barrier(0);
        }
    }

    // epilogue
    float* op = out + (size_t)bz * 16384;
    #pragma unroll
    for (int mt = 0; mt < 2; ++mt)
        #pragma unroll
        for (int nt = 0; nt < 4; ++nt)
            #pragma unroll
            for (int r = 0; r < 4; ++r) {
                int x = g4 * 32 + mt * 16 + l4 * 4 + r;
                int y = g2 * 64 + nt * 16 + l15;
                if (first) op[x * 128 + y] = acc[mt][nt][r];
                else       op[x * 128 + y] += acc[mt][nt][r];
            }
}

extern "C" void kernel_launch(void* const* d_in, const int* in_sizes, int n_in,
                              void* d_out, int out_size, void* d_ws, size_t ws_size,
                              hipStream_t stream)
{
    const float* x = (const float*)d_in[0];
    const float* y = (const float*)d_in[1];
    const float* z = (const float*)d_in[2];
    const float* w = (const float*)d_in[3];
    float* out = (float*)d_out;
    char* ws = (char*)d_ws;

    unsigned short* xbf = (unsigned short*)(ws + 0);
    unsigned short* ybf = (unsigned short*)(ws + 524288);
    unsigned short* zbf = (unsigned short*)(ws + 1048576);
    float* a_arr = (float*)(ws + 1572864);
    float* c_arr = (float*)(ws + 2621440);
    float* d_arr = (float*)(ws + 3670016);
    unsigned short* Mws = (unsigned short*)(ws + 3674112);

    size_t avail = (ws_size > 3674112) ? ws_size - 3674112 : 0;
    int chi = 512;                                   // i-rows of M materialized per chunk
    while (chi > 128 && (size_t)chi * 524288 > avail) chi >>= 1;

    hipLaunchKernelGGL(k_cast, dim3(384), dim3(256), 0, stream, x, y, z, xbf, ybf, zbf);
    hipLaunchKernelGGL(k_edge, dim3(136), dim3(256), 0, stream, z, w, a_arr, c_arr, d_arr);

    int nch = 512 / chi;
    for (int c = 0; c < nch; ++c) {
        int i0 = c * chi;
        hipLaunchKernelGGL(k_gemm1, dim3(chi * 4), dim3(512), 81920, stream, zbf, w, Mws, i0, chi);
        hipLaunchKernelGGL(k_fuse, dim3(512), dim3(512), 131072, stream, xbf, ybf, Mws,
                           x, y, a_arr, c_arr, d_arr, out, i0, chi / 128, chi, (c == 0) ? 1 : 0);
    }
}